// Round 2
// baseline (481.220 us; speedup 1.0000x reference)
//
#include <hip/hip_runtime.h>

typedef __attribute__((ext_vector_type(8))) short short8;
typedef __attribute__((ext_vector_type(4))) float f32x4;
typedef __attribute__((ext_vector_type(2))) float f32x2;
typedef __attribute__((ext_vector_type(4))) unsigned int uint4v;

#define NI 2048   // input capsules
// B=64, J=32, D=16, E=16, JD=512. Inputs fp32 (per reference), compute bf16 MFMA.

// bf16 round-to-nearest-even pack of two floats -> dword (lo=a, hi=b)
__device__ __forceinline__ unsigned int packbf2(float a, float b){
  unsigned int ua = __float_as_uint(a), ub = __float_as_uint(b);
  unsigned int ra = (ua + 0x7FFFu + ((ua >> 16) & 1u)) >> 16;
  unsigned int rb = (ub + 0x7FFFu + ((ub >> 16) & 1u)) & 0xFFFF0000u;
  return ra | rb;
}
__device__ __forceinline__ float bflo(unsigned int p){ return __uint_as_float(p << 16); }
__device__ __forceinline__ float bfhi(unsigned int p){ return __uint_as_float(p & 0xFFFF0000u); }

// convert 8 contiguous fp32 -> 8 bf16 (as uint4) for LDS staging
__device__ __forceinline__ uint4v cvt8(const f32x4& a, const f32x4& b){
  uint4v p = { packbf2(a.x, a.y), packbf2(a.z, a.w),
               packbf2(b.x, b.y), packbf2(b.z, b.w) };
  return p;
}

// MODE 0: uniform c (pure GEMM, 2 i's packed into K=32) -> partials of sum_i u
// MODE 1: c = softmax_j( sum_d u * v ) -> partials of sum_i c*u
// Block: 512 threads = 8 waves = (4 b-tiles) x (2 j-halves). Covers all 64 b,
// i-chunk of CI. Partials layout: [blk][w][lane][64]  (64 = 16 tiles x 4 regs)
template<int MODE>
__global__ __launch_bounds__(512)
void caps_pass(const float* __restrict__ Wg,   // fp32 [NI][J*D*E]=[NI][8192]
               const float* __restrict__ Xg,   // fp32 [64][NI][16]
               const float* __restrict__ vbuf, // [64][512] (MODE 1)
               float* __restrict__ partials,
               int CI)
{
  constexpr int WROWS = (MODE == 0) ? 2 : 1;
  __shared__ __align__(16) unsigned short sW[2][WROWS * 8192];
  __shared__ __align__(16) unsigned int   sXd[2][WROWS * 512];
  __shared__ float sLog[(MODE == 1) ? (64 * 33) : 4];

  const int t     = threadIdx.x;
  const int w     = t >> 6;
  const int lane  = t & 63;
  const int wtile = w & 3;        // b-tile
  const int jhalf = w >> 2;       // j-half
  const int lq    = lane >> 4;    // quad within wave
  const int lb    = lane & 15;
  const int q1    = lq & 1;
  const int bg    = wtile * 16 + lb;          // this lane's b (C/D col)
  const size_t i0base = (size_t)blockIdx.x * (size_t)CI;

  const short8 zero8 = {0,0,0,0,0,0,0,0};
  const f32x4  zf4   = {0.f,0.f,0.f,0.f};

  f32x4 acc[16];
  #pragma unroll
  for (int tj = 0; tj < 16; ++tj) acc[tj] = zf4;

  // v resident in regs across the whole i-loop (does not depend on i)
  f32x4 vreg[16];
  if constexpr (MODE == 1){
    #pragma unroll
    for (int tj = 0; tj < 16; ++tj)
      vreg[tj] = *(const f32x4*)(&vbuf[bg * 512 + (jhalf * 16 + tj) * 16 + lq * 4]);
  }

  const int NSTEP = CI / WROWS;

  // stage step 0 into buffer 0 (fp32 load -> bf16 pack -> LDS)
  {
    const float* wsrc = Wg + i0base * 8192;
    #pragma unroll
    for (int r = 0; r < WROWS * 2; ++r){
      int c = r * 512 + t;
      f32x4 a = *(const f32x4*)(&wsrc[c * 8]);
      f32x4 b = *(const f32x4*)(&wsrc[c * 8 + 4]);
      *(uint4v*)(&sW[0][c * 8]) = cvt8(a, b);
    }
    #pragma unroll
    for (int r = 0; r < WROWS; ++r){
      int bidx = t >> 3, e2 = t & 7;
      size_t irow = i0base + (size_t)r;
      f32x2 xv = *(const f32x2*)(&Xg[((size_t)bidx * NI + irow) * 16 + e2 * 2]);
      sXd[0][r * 512 + t] = packbf2(xv.x, xv.y);
    }
  }
  __syncthreads();

  for (int s = 0; s < NSTEP; ++s){
    const int buf = s & 1;

    // issue prefetch for next step (overlaps with compute)
    f32x4 wpa[WROWS * 2], wpb[WROWS * 2];
    f32x2 xp[WROWS];
    const bool more = (s + 1 < NSTEP);
    if (more){
      const float* wsrc = Wg + (i0base + (size_t)(s + 1) * WROWS) * 8192;
      #pragma unroll
      for (int r = 0; r < WROWS * 2; ++r){
        int c = r * 512 + t;
        wpa[r] = *(const f32x4*)(&wsrc[c * 8]);
        wpb[r] = *(const f32x4*)(&wsrc[c * 8 + 4]);
      }
      #pragma unroll
      for (int r = 0; r < WROWS; ++r){
        int bidx = t >> 3, e2 = t & 7;
        size_t irow = i0base + (size_t)(s + 1) * WROWS + (size_t)r;
        xp[r] = *(const f32x2*)(&Xg[((size_t)bidx * NI + irow) * 16 + e2 * 2]);
      }
    }

    const unsigned short* xrow = (const unsigned short*)&sXd[buf][0];

    if constexpr (MODE == 0){
      // K=32 = (e 0..15 of i0) ++ (e 0..15 of i1): quads 0,1 -> i0; 2,3 -> i1
      const int rsel = lq >> 1;
      short8 bfrag = *(const short8*)(&xrow[rsel * 1024 + bg * 16 + q1 * 8]);
      #pragma unroll
      for (int tj = 0; tj < 16; ++tj){
        int j = jhalf * 16 + tj;
        short8 afrag = *(const short8*)(&sW[buf][rsel * 8192 + j * 256 + lb * 16 + q1 * 8]);
        acc[tj] = __builtin_amdgcn_mfma_f32_16x16x32_bf16(afrag, bfrag, acc[tj], 0, 0, 0);
      }
    } else {
      // K upper half zero (quads 2,3). A[m=d][k=e]=W[i][j][d][e], B[k=e][n=b]=x[b][e]
      short8 bl8 = *(const short8*)(&xrow[bg * 16 + q1 * 8]);
      short8 bfrag = (lq < 2) ? bl8 : zero8;
      unsigned int ulo[16], uhi[16];
      #pragma unroll
      for (int tj = 0; tj < 16; ++tj){
        int j = jhalf * 16 + tj;
        short8 al8 = *(const short8*)(&sW[buf][j * 256 + lb * 16 + q1 * 8]);
        short8 afrag = (lq < 2) ? al8 : zero8;
        f32x4 u = __builtin_amdgcn_mfma_f32_16x16x32_bf16(afrag, bfrag, zf4, 0, 0, 0);
        // logit partial: sum_d u*v ; rows of this tile are d = lq*4+r
        float p = u.x * vreg[tj].x + u.y * vreg[tj].y + u.z * vreg[tj].z + u.w * vreg[tj].w;
        p += __shfl_xor(p, 16, 64);
        p += __shfl_xor(p, 32, 64);   // all lanes now hold logit[j][b=col]
        if (lane < 16) sLog[bg * 33 + j] = p;
        ulo[tj] = packbf2(u.x, u.y);  // keep u packed for phase 2
        uhi[tj] = packbf2(u.z, u.w);
      }
      __syncthreads();
      // per-lane softmax over all 32 j for this lane's b
      const float* logrow = &sLog[bg * 33];
      float lt[32];
      float m = -1e30f;
      #pragma unroll
      for (int jj = 0; jj < 32; ++jj){ lt[jj] = logrow[jj]; m = fmaxf(m, lt[jj]); }
      float ssum = 0.f;
      #pragma unroll
      for (int jj = 0; jj < 32; ++jj){ float e = __expf(lt[jj] - m); lt[jj] = e; ssum += e; }
      float inv = 1.0f / ssum;
      #pragma unroll
      for (int tj = 0; tj < 16; ++tj){
        float c = lt[jhalf * 16 + tj] * inv;
        acc[tj].x += c * bflo(ulo[tj]);
        acc[tj].y += c * bfhi(ulo[tj]);
        acc[tj].z += c * bflo(uhi[tj]);
        acc[tj].w += c * bfhi(uhi[tj]);
      }
    }

    if (more){
      const int nb = buf ^ 1;
      #pragma unroll
      for (int r = 0; r < WROWS * 2; ++r){
        int c = r * 512 + t;
        *(uint4v*)(&sW[nb][c * 8]) = cvt8(wpa[r], wpb[r]);
      }
      #pragma unroll
      for (int r = 0; r < WROWS; ++r)
        sXd[nb][r * 512 + t] = packbf2(xp[r].x, xp[r].y);
    }
    __syncthreads();
  }

  float* dst = partials + (((size_t)blockIdx.x * 8 + (size_t)w) * 64 + (size_t)lane) * 64;
  #pragma unroll
  for (int tj = 0; tj < 16; ++tj) *(f32x4*)(dst + tj * 4) = acc[tj];
}

// Sum partials over blocks (fully coalesced: element T at stride 32768) and
// un-permute (w,l,k) -> [b][jd] into S_buf.
__global__ __launch_bounds__(256)
void caps_reduce(const float* __restrict__ partials, float* __restrict__ S_buf,
                 float scale, int nblk)
{
  const int T = blockIdx.x * 256 + threadIdx.x;   // 0..32767
  float s = 0.f;
  for (int bl = 0; bl < nblk; ++bl) s += partials[(size_t)bl * 32768 + T];
  s *= scale;
  const int w = T >> 12, l = (T >> 6) & 63, k = T & 63;
  const int b  = (w & 3) * 16 + (l & 15);
  const int jd = (w >> 2) * 256 + (k >> 2) * 16 + ((l >> 4) << 2) + (k & 3);
  S_buf[b * 512 + jd] = s;
}

// squash over capsule axis J (axis=2 of [B,1,J,D]): sq[b][d] = sum_j S^2
// vout = squash(S) (+ vprev if given)
__global__ __launch_bounds__(256)
void caps_squash_j(const float* __restrict__ S, const float* __restrict__ vprev,
                   float* __restrict__ vout)
{
  const int b = blockIdx.x, t = threadIdx.x;
  __shared__ float sq[16];
  if (t < 16) sq[t] = 0.f;
  __syncthreads();
  float s0 = S[b * 512 + t], s1 = S[b * 512 + 256 + t];
  atomicAdd(&sq[t & 15], s0 * s0 + s1 * s1);   // (t+256)&15 == t&15
  __syncthreads();
  float q = sq[t & 15];
  float f = q / ((1.f + q) * sqrtf(q + 1e-8f));
  float v0 = s0 * f, v1 = s1 * f;
  if (vprev){ v0 += vprev[b * 512 + t]; v1 += vprev[b * 512 + 256 + t]; }
  vout[b * 512 + t] = v0;
  vout[b * 512 + 256 + t] = v1;
}

// final squash over D (axis=-1): sq[b][j] = sum_d S^2 ; fp32 output [B][J][D]
__global__ __launch_bounds__(256)
void caps_squash_d(const float* __restrict__ S, float* __restrict__ out)
{
  const int b = blockIdx.x, t = threadIdx.x;
  __shared__ float sq[32];
  if (t < 32) sq[t] = 0.f;
  __syncthreads();
  float s0 = S[b * 512 + t], s1 = S[b * 512 + 256 + t];
  atomicAdd(&sq[t >> 4], s0 * s0);
  atomicAdd(&sq[(t + 256) >> 4], s1 * s1);
  __syncthreads();
  float q0 = sq[t >> 4], q1 = sq[(t + 256) >> 4];
  out[b * 512 + t]       = s0 * q0 / ((1.f + q0) * sqrtf(q0 + 1e-8f));
  out[b * 512 + 256 + t] = s1 * q1 / ((1.f + q1) * sqrtf(q1 + 1e-8f));
}

extern "C" void kernel_launch(void* const* d_in, const int* in_sizes, int n_in,
                              void* d_out, int out_size, void* d_ws, size_t ws_size,
                              hipStream_t stream)
{
  const float* X = (const float*)d_in[0];  // x fp32 [64][2048][16]
  const float* W = (const float*)d_in[1];  // weight fp32 [2048][32][16][16] (leading 1 dropped)
  float* wsf = (float*)d_ws;

  // workspace ladder: partials need NBLK*32768 floats (+3*32768 for S/v1/v12)
  int NBLK = 256;
  auto need = [](int nb){ return ((size_t)nb * 32768 + 3 * 32768) * 4; };
  if (ws_size < need(256)){
    if      (ws_size >= need(64)) NBLK = 64;
    else if (ws_size >= need(16)) NBLK = 16;
    else                          NBLK = 4;
  }
  const int CI = NI / NBLK;

  float* partials = wsf;
  float* sbuf = wsf + (size_t)NBLK * 32768;
  float* v1   = sbuf + 32768;
  float* v12  = v1 + 32768;

  // pass A: c = 1/32 uniform -> v1 = squash_J(S1)
  caps_pass<0><<<dim3(NBLK), dim3(512), 0, stream>>>(W, X, nullptr, partials, CI);
  caps_reduce<<<dim3(128), dim3(256), 0, stream>>>(partials, sbuf, 1.0f / 32.0f, NBLK);
  caps_squash_j<<<dim3(64), dim3(256), 0, stream>>>(sbuf, nullptr, v1);
  // pass B: c = softmax_j(u.v1) -> v12 = v1 + squash_J(S2)
  caps_pass<1><<<dim3(NBLK), dim3(512), 0, stream>>>(W, X, v1, partials, CI);
  caps_reduce<<<dim3(128), dim3(256), 0, stream>>>(partials, sbuf, 1.0f, NBLK);
  caps_squash_j<<<dim3(64), dim3(256), 0, stream>>>(sbuf, v1, v12);
  // pass C: b2 = u.(v1+v2) -> out = squash_D(S3)
  caps_pass<1><<<dim3(NBLK), dim3(512), 0, stream>>>(W, X, v12, partials, CI);
  caps_reduce<<<dim3(128), dim3(256), 0, stream>>>(partials, sbuf, 1.0f, NBLK);
  caps_squash_d<<<dim3(64), dim3(256), 0, stream>>>(sbuf, (float*)d_out);
}

// Round 3
// 323.140 us; speedup vs baseline: 1.4892x; 1.4892x over previous
//
#include <hip/hip_runtime.h>

typedef __attribute__((ext_vector_type(8))) short short8;
typedef __attribute__((ext_vector_type(4))) float f32x4;
typedef __attribute__((ext_vector_type(2))) float f32x2;
typedef __attribute__((ext_vector_type(4))) unsigned int uint4v;

#define NI 2048   // input capsules
// B=64, J=32, D=16, E=16, JD=512. Inputs fp32 (per reference), compute bf16 MFMA.

// bf16 RNE pack of two floats -> dword (lo=a, hi=b)
__device__ __forceinline__ unsigned int packbf2(float a, float b){
  unsigned int ua = __float_as_uint(a), ub = __float_as_uint(b);
  unsigned int ra = (ua + 0x7FFFu + ((ua >> 16) & 1u)) >> 16;
  unsigned int rb = (ub + 0x7FFFu + ((ub >> 16) & 1u)) & 0xFFFF0000u;
  return ra | rb;
}
__device__ __forceinline__ float bflo(unsigned int p){ return __uint_as_float(p << 16); }
__device__ __forceinline__ float bfhi(unsigned int p){ return __uint_as_float(p & 0xFFFF0000u); }

__device__ __forceinline__ uint4v cvt8(const f32x4& a, const f32x4& b){
  uint4v p = { packbf2(a.x, a.y), packbf2(a.z, a.w),
               packbf2(b.x, b.y), packbf2(b.z, b.w) };
  return p;
}

// MODE 0: uniform c (scale applied in reduce) -> partials of sum_i u
// MODE 1: c = softmax_j( sum_d u * v ) -> partials of sum_i c*u
// Block: 256 threads = 4 waves = (2 b-tiles) x (2 j-halves), covers 32 b
// (bhalf = blockIdx.x & 1). i-chunk of CI (iblk = blockIdx.x >> 1).
// Partials: [blk][w][lane][64] (64 = 16 j-tiles x 4 d-regs).
template<int MODE>
__global__ __launch_bounds__(256)
void caps_pass(const float* __restrict__ Wg,   // fp32 [NI][8192]  (J*D*E)
               const float* __restrict__ Xg,   // fp32 [64][NI][16]
               const float* __restrict__ vbuf, // fp32 [64][512] (MODE 1)
               float* __restrict__ partials,
               int CI)
{
  __shared__ __align__(16) unsigned short sW[2][8192];   // one W row, bf16
  __shared__ __align__(16) unsigned int   sXd[2][256];   // 32 b x 16 e, bf16
  __shared__ float sLog[(MODE == 1) ? (32 * 33) : 4];

  const int t      = threadIdx.x;       // 0..255
  const int w      = t >> 6;            // 0..3
  const int lane   = t & 63;
  const int wtile  = w & 1;             // b-tile within half
  const int jhalf  = w >> 1;            // j-half
  const int lq     = lane >> 4;         // quad
  const int lb     = lane & 15;
  const int q1     = lq & 1;
  const int bhalf  = blockIdx.x & 1;
  const int iblk   = blockIdx.x >> 1;
  const int bloc   = wtile * 16 + lb;   // b within half (0..31)
  const int bg     = bhalf * 32 + bloc; // global b
  const size_t i0  = (size_t)iblk * (size_t)CI;

  const short8 zero8 = {0,0,0,0,0,0,0,0};
  const f32x4  zf4   = {0.f,0.f,0.f,0.f};

  f32x4 acc[16];
  #pragma unroll
  for (int tj = 0; tj < 16; ++tj) acc[tj] = zf4;

  // v for logits, packed bf16: 32 VGPRs instead of 64
  unsigned int vpl[16], vph[16];
  if constexpr (MODE == 1){
    #pragma unroll
    for (int tj = 0; tj < 16; ++tj){
      f32x4 v = *(const f32x4*)(&vbuf[bg * 512 + (jhalf * 16 + tj) * 16 + lq * 4]);
      vpl[tj] = packbf2(v.x, v.y);
      vph[tj] = packbf2(v.z, v.w);
    }
  }

  // stage step 0 into buffer 0 (fp32 -> bf16 -> LDS)
  {
    const float* wsrc = Wg + i0 * 8192;
    #pragma unroll
    for (int r = 0; r < 4; ++r){
      int c = r * 256 + t;
      f32x4 a = *(const f32x4*)(&wsrc[c * 8]);
      f32x4 b = *(const f32x4*)(&wsrc[c * 8 + 4]);
      *(uint4v*)(&sW[0][c * 8]) = cvt8(a, b);
    }
    int bidx = bhalf * 32 + (t >> 3), e2 = t & 7;
    f32x2 xv = *(const f32x2*)(&Xg[((size_t)bidx * NI + i0) * 16 + e2 * 2]);
    sXd[0][t] = packbf2(xv.x, xv.y);
  }
  __syncthreads();

  for (int s = 0; s < CI; ++s){
    const int buf = s & 1;

    // prefetch next W row + x slice into registers (overlaps compute)
    f32x4 wpa[4], wpb[4];
    f32x2 xp;
    const bool more = (s + 1 < CI);
    if (more){
      const float* wsrc = Wg + (i0 + (size_t)(s + 1)) * 8192;
      #pragma unroll
      for (int r = 0; r < 4; ++r){
        int c = r * 256 + t;
        wpa[r] = *(const f32x4*)(&wsrc[c * 8]);
        wpb[r] = *(const f32x4*)(&wsrc[c * 8 + 4]);
      }
      int bidx = bhalf * 32 + (t >> 3), e2 = t & 7;
      xp = *(const f32x2*)(&Xg[((size_t)bidx * NI + i0 + s + 1) * 16 + e2 * 2]);
    }

    const unsigned short* xrow = (const unsigned short*)&sXd[buf][0];
    // B fragment: B[k=e][n=b], K upper half zero (quads 2,3)
    short8 bl8 = *(const short8*)(&xrow[bloc * 16 + q1 * 8]);
    short8 bfrag = (lq < 2) ? bl8 : zero8;

    if constexpr (MODE == 0){
      #pragma unroll
      for (int tj = 0; tj < 16; ++tj){
        int j = jhalf * 16 + tj;
        short8 al8 = *(const short8*)(&sW[buf][j * 256 + lb * 16 + q1 * 8]);
        short8 afrag = (lq < 2) ? al8 : zero8;
        acc[tj] = __builtin_amdgcn_mfma_f32_16x16x32_bf16(afrag, bfrag, acc[tj], 0, 0, 0);
      }
    } else {
      // phase 1: u tiles -> logits into sLog (u NOT kept: recomputed in phase 2)
      #pragma unroll
      for (int tj = 0; tj < 16; ++tj){
        int j = jhalf * 16 + tj;
        short8 al8 = *(const short8*)(&sW[buf][j * 256 + lb * 16 + q1 * 8]);
        short8 afrag = (lq < 2) ? al8 : zero8;
        f32x4 u = __builtin_amdgcn_mfma_f32_16x16x32_bf16(afrag, bfrag, zf4, 0, 0, 0);
        float p = u.x * bflo(vpl[tj]) + u.y * bfhi(vpl[tj])
                + u.z * bflo(vph[tj]) + u.w * bfhi(vph[tj]);
        p += __shfl_xor(p, 16, 64);
        p += __shfl_xor(p, 32, 64);          // full logit[j][b] in all lanes
        if (lane < 16) sLog[bloc * 33 + j] = p;
      }
      __syncthreads();
      // per-lane softmax scalars over all 32 j for this lane's b
      const float* logrow = &sLog[bloc * 33];
      float m = -1e30f;
      #pragma unroll
      for (int jj = 0; jj < 32; ++jj) m = fmaxf(m, logrow[jj]);
      float ssum = 0.f;
      #pragma unroll
      for (int jj = 0; jj < 32; ++jj) ssum += __expf(logrow[jj] - m);
      float inv = 1.0f / ssum;
      // phase 2: recompute u, apply c
      #pragma unroll
      for (int tj = 0; tj < 16; ++tj){
        int j = jhalf * 16 + tj;
        short8 al8 = *(const short8*)(&sW[buf][j * 256 + lb * 16 + q1 * 8]);
        short8 afrag = (lq < 2) ? al8 : zero8;
        f32x4 u = __builtin_amdgcn_mfma_f32_16x16x32_bf16(afrag, bfrag, zf4, 0, 0, 0);
        float c = __expf(logrow[j] - m) * inv;
        acc[tj].x += c * u.x;
        acc[tj].y += c * u.y;
        acc[tj].z += c * u.z;
        acc[tj].w += c * u.w;
      }
    }

    if (more){
      const int nb = buf ^ 1;
      #pragma unroll
      for (int r = 0; r < 4; ++r){
        int c = r * 256 + t;
        *(uint4v*)(&sW[nb][c * 8]) = cvt8(wpa[r], wpb[r]);
      }
      sXd[nb][t] = packbf2(xp.x, xp.y);
    }
    __syncthreads();
  }

  float* dst = partials + ((size_t)blockIdx.x * 4 + (size_t)w) * 4096 + (size_t)lane * 64;
  #pragma unroll
  for (int tj = 0; tj < 16; ++tj) *(f32x4*)(dst + tj * 4) = acc[tj];
}

// Sum partials over i-blocks (element T, plane stride 32768; fully coalesced,
// unrolled with 4 independent accumulators) and un-permute into S_buf[b][jd].
template<int NBLK>
__global__ __launch_bounds__(128)
void caps_reduce(const float* __restrict__ partials, float* __restrict__ S_buf,
                 float scale)
{
  const int T = blockIdx.x * 128 + threadIdx.x;   // 0..32767
  float s0 = 0.f, s1 = 0.f, s2 = 0.f, s3 = 0.f;
  #pragma unroll
  for (int bl = 0; bl < NBLK; bl += 4){
    s0 += partials[(size_t)(bl + 0) * 32768 + T];
    s1 += partials[(size_t)(bl + 1) * 32768 + T];
    s2 += partials[(size_t)(bl + 2) * 32768 + T];
    s3 += partials[(size_t)(bl + 3) * 32768 + T];
  }
  float s = ((s0 + s1) + (s2 + s3)) * scale;
  const int bhalf = T >> 14, w = (T >> 12) & 3, l = (T >> 6) & 63, k = T & 63;
  const int b  = bhalf * 32 + (w & 1) * 16 + (l & 15);
  const int jd = ((w >> 1) * 16 + (k >> 2)) * 16 + ((l >> 4) << 2) + (k & 3);
  S_buf[b * 512 + jd] = s;
}

// squash over capsule axis J: sq[b][d] = sum_j S^2 ; vout = squash(S) (+ vprev)
__global__ __launch_bounds__(256)
void caps_squash_j(const float* __restrict__ S, const float* __restrict__ vprev,
                   float* __restrict__ vout)
{
  const int b = blockIdx.x, t = threadIdx.x;
  __shared__ float sq[16];
  if (t < 16) sq[t] = 0.f;
  __syncthreads();
  float s0 = S[b * 512 + t], s1 = S[b * 512 + 256 + t];
  atomicAdd(&sq[t & 15], s0 * s0 + s1 * s1);
  __syncthreads();
  float q = sq[t & 15];
  float f = q / ((1.f + q) * sqrtf(q + 1e-8f));
  float v0 = s0 * f, v1 = s1 * f;
  if (vprev){ v0 += vprev[b * 512 + t]; v1 += vprev[b * 512 + 256 + t]; }
  vout[b * 512 + t] = v0;
  vout[b * 512 + 256 + t] = v1;
}

// final squash over D (axis=-1): fp32 output [B][J][D]
__global__ __launch_bounds__(256)
void caps_squash_d(const float* __restrict__ S, float* __restrict__ out)
{
  const int b = blockIdx.x, t = threadIdx.x;
  __shared__ float sq[32];
  if (t < 32) sq[t] = 0.f;
  __syncthreads();
  float s0 = S[b * 512 + t], s1 = S[b * 512 + 256 + t];
  atomicAdd(&sq[t >> 4], s0 * s0);
  atomicAdd(&sq[(t + 256) >> 4], s1 * s1);
  __syncthreads();
  float q0 = sq[t >> 4], q1 = sq[(t + 256) >> 4];
  out[b * 512 + t]       = s0 * q0 / ((1.f + q0) * sqrtf(q0 + 1e-8f));
  out[b * 512 + 256 + t] = s1 * q1 / ((1.f + q1) * sqrtf(q1 + 1e-8f));
}

extern "C" void kernel_launch(void* const* d_in, const int* in_sizes, int n_in,
                              void* d_out, int out_size, void* d_ws, size_t ws_size,
                              hipStream_t stream)
{
  const float* X = (const float*)d_in[0];  // fp32 [64][2048][16]
  const float* W = (const float*)d_in[1];  // fp32 [2048][32][16][16]
  float* wsf = (float*)d_ws;

  // NBI = number of i-blocks; pass grid = 2*NBI; partials = NBI*32768 floats
  int NBI = 256;
  auto need = [](int nb){ return ((size_t)nb * 32768 + 3 * 32768) * 4; };
  if (ws_size < need(256)){
    if      (ws_size >= need(64)) NBI = 64;
    else if (ws_size >= need(16)) NBI = 16;
    else                          NBI = 4;
  }
  const int CI = NI / NBI;

  float* partials = wsf;
  float* sbuf = wsf + (size_t)NBI * 32768;
  float* v1   = sbuf + 32768;
  float* v12  = v1 + 32768;

  auto reduce = [&](float scale){
    if      (NBI == 256) caps_reduce<256><<<dim3(256), dim3(128), 0, stream>>>(partials, sbuf, scale);
    else if (NBI ==  64) caps_reduce< 64><<<dim3(256), dim3(128), 0, stream>>>(partials, sbuf, scale);
    else if (NBI ==  16) caps_reduce< 16><<<dim3(256), dim3(128), 0, stream>>>(partials, sbuf, scale);
    else                 caps_reduce<  4><<<dim3(256), dim3(128), 0, stream>>>(partials, sbuf, scale);
  };

  // pass A: uniform c -> v1 = squash_J(S1)
  caps_pass<0><<<dim3(2 * NBI), dim3(256), 0, stream>>>(W, X, nullptr, partials, CI);
  reduce(1.0f / 32.0f);
  caps_squash_j<<<dim3(64), dim3(256), 0, stream>>>(sbuf, nullptr, v1);
  // pass B: c = softmax_j(u.v1) -> v12 = v1 + squash_J(S2)
  caps_pass<1><<<dim3(2 * NBI), dim3(256), 0, stream>>>(W, X, v1, partials, CI);
  reduce(1.0f);
  caps_squash_j<<<dim3(64), dim3(256), 0, stream>>>(sbuf, v1, v12);
  // pass C: logits u.(v1+v2) -> out = squash_D(S3)
  caps_pass<1><<<dim3(2 * NBI), dim3(256), 0, stream>>>(W, X, v12, partials, CI);
  reduce(1.0f);
  caps_squash_d<<<dim3(64), dim3(256), 0, stream>>>(sbuf, (float*)d_out);
}

// Round 4
// 292.555 us; speedup vs baseline: 1.6449x; 1.1045x over previous
//
#include <hip/hip_runtime.h>

typedef __attribute__((ext_vector_type(8))) short short8;
typedef __attribute__((ext_vector_type(4))) float f32x4;
typedef __attribute__((ext_vector_type(2))) float f32x2;
typedef __attribute__((ext_vector_type(4))) unsigned int uint4v;
typedef unsigned short u16;

#define NI 2048   // input capsules
// B=64, J=32, D=16, E=16, JD=512. Inputs fp32; compute bf16 MFMA.

// bf16 RNE pack of two floats -> dword (lo=a, hi=b)
__device__ __forceinline__ unsigned int packbf2(float a, float b){
  unsigned int ua = __float_as_uint(a), ub = __float_as_uint(b);
  unsigned int ra = (ua + 0x7FFFu + ((ua >> 16) & 1u)) >> 16;
  unsigned int rb = (ub + 0x7FFFu + ((ub >> 16) & 1u)) & 0xFFFF0000u;
  return ra | rb;
}
__device__ __forceinline__ float bflo(unsigned int p){ return __uint_as_float(p << 16); }
__device__ __forceinline__ float bfhi(unsigned int p){ return __uint_as_float(p & 0xFFFF0000u); }

__device__ __forceinline__ uint4v cvt8(const f32x4& a, const f32x4& b){
  uint4v p = { packbf2(a.x, a.y), packbf2(a.z, a.w),
               packbf2(b.x, b.y), packbf2(b.z, b.w) };
  return p;
}

// async global->LDS, 16 B per lane; lds dest = wave-uniform base + lane*16
__device__ __forceinline__ void gl_lds16(const void* g, void* l){
  __builtin_amdgcn_global_load_lds(
      (const __attribute__((address_space(1))) unsigned int*)g,
      (__attribute__((address_space(3))) unsigned int*)l, 16, 0, 0);
}

// ---------------- prep: W fp32->bf16 (same layout), X fp32->bf16 transposed to [i][b][e]
__global__ __launch_bounds__(256)
void caps_prep(const float* __restrict__ W, const float* __restrict__ X,
               u16* __restrict__ Wb, u16* __restrict__ Xb)
{
  const int bid = blockIdx.x;
  if (bid < 8192){
    size_t base = (size_t)bid * 2048 + (size_t)threadIdx.x * 8;
    f32x4 a = *(const f32x4*)(W + base);
    f32x4 b = *(const f32x4*)(W + base + 4);
    *(uint4v*)(Wb + base) = cvt8(a, b);
  } else {
    int p = (bid - 8192) * 256 + threadIdx.x;   // 0..131071 = (i,b)
    int i = p >> 6, b = p & 63;
    const float* src = X + ((size_t)b * NI + i) * 16;
    f32x4 a0 = *(const f32x4*)(src);
    f32x4 a1 = *(const f32x4*)(src + 4);
    f32x4 a2 = *(const f32x4*)(src + 8);
    f32x4 a3 = *(const f32x4*)(src + 12);
    *(uint4v*)(Xb + (size_t)p * 16)     = cvt8(a0, a1);
    *(uint4v*)(Xb + (size_t)p * 16 + 8) = cvt8(a2, a3);
  }
}

// ---------------- fast pass (bf16 inputs, async staging, batched softmax)
// MODE 0: uniform c -> partials of sum_i u ; MODE 1: c = softmax_j(u.v) -> sum_i c*u
// Block: 256 thr = 4 waves = (2 b-tiles)x(2 j-halves); bhalf = blockIdx.x&1.
template<int MODE>
__global__ __launch_bounds__(256)
void caps_pass_f(const u16* __restrict__ Wb,   // bf16 [NI][8192]
                 const u16* __restrict__ Xb,   // bf16 [NI][64][16]  (transposed)
                 const float* __restrict__ vbuf,
                 float* __restrict__ partials, int CI)
{
  __shared__ __align__(16) u16 sW[2][8192];
  __shared__ __align__(16) u16 sX[2][512];
  __shared__ __align__(16) float sLog[(MODE == 1) ? (32 * 36) : 4];

  const int t     = threadIdx.x;
  const int w     = t >> 6;
  const int lane  = t & 63;
  const int wtile = w & 1;
  const int jhalf = w >> 1;
  const int lq    = lane >> 4;
  const int lb    = lane & 15;
  const int q1    = lq & 1;
  const int bhalf = blockIdx.x & 1;
  const int iblk  = blockIdx.x >> 1;
  const int bloc  = wtile * 16 + lb;
  const int bg    = bhalf * 32 + bloc;
  const size_t i0 = (size_t)iblk * (size_t)CI;

  const short8 zero8 = {0,0,0,0,0,0,0,0};
  const f32x4  zf4   = {0.f,0.f,0.f,0.f};

  f32x4 acc[16];
  #pragma unroll
  for (int tj = 0; tj < 16; ++tj) acc[tj] = zf4;

  unsigned int vpl[16], vph[16];
  if constexpr (MODE == 1){
    #pragma unroll
    for (int tj = 0; tj < 16; ++tj){
      f32x4 v = *(const f32x4*)(&vbuf[bg * 512 + (jhalf * 16 + tj) * 16 + lq * 4]);
      vpl[tj] = packbf2(v.x, v.y);
      vph[tj] = packbf2(v.z, v.w);
    }
  }

  // async stage of row irow into buffer nb: W 16 KB (4 waves x 4 issues x 1 KB),
  // X 1 KB (wave 3, 1 issue)
  auto stage = [&](int nb, size_t irow){
    const u16* src = Wb + irow * 8192 + (size_t)(w * 4) * 512;
    u16* dst = &sW[nb][w * 4 * 512];
    #pragma unroll
    for (int r = 0; r < 4; ++r)
      gl_lds16(src + r * 512 + lane * 8, dst + r * 512);
    if (w == 3)
      gl_lds16(Xb + (irow * 64 + (size_t)bhalf * 32) * 16 + lane * 8, &sX[nb][0]);
  };

  stage(0, i0);
  __syncthreads();

  for (int s = 0; s < CI; ++s){
    const int buf = s & 1;
    if (s + 1 < CI) stage(buf ^ 1, i0 + s + 1);   // async, drained by barrier

    short8 bl8 = *(const short8*)(&sX[buf][bloc * 16 + q1 * 8]);
    short8 bfrag = (lq < 2) ? bl8 : zero8;        // K upper half zero

    if constexpr (MODE == 0){
      #pragma unroll
      for (int tj = 0; tj < 16; ++tj){
        int j = jhalf * 16 + tj;
        short8 al8 = *(const short8*)(&sW[buf][j * 256 + lb * 16 + q1 * 8]);
        short8 afrag = (lq < 2) ? al8 : zero8;
        acc[tj] = __builtin_amdgcn_mfma_f32_16x16x32_bf16(afrag, bfrag, acc[tj], 0, 0, 0);
      }
    } else {
      // phase 1: u -> logits into sLog[b][j] (row stride 36)
      #pragma unroll
      for (int tj = 0; tj < 16; ++tj){
        int j = jhalf * 16 + tj;
        short8 al8 = *(const short8*)(&sW[buf][j * 256 + lb * 16 + q1 * 8]);
        short8 afrag = (lq < 2) ? al8 : zero8;
        f32x4 u = __builtin_amdgcn_mfma_f32_16x16x32_bf16(afrag, bfrag, zf4, 0, 0, 0);
        float p = u.x * bflo(vpl[tj]) + u.y * bfhi(vpl[tj])
                + u.z * bflo(vph[tj]) + u.w * bfhi(vph[tj]);
        p += __shfl_xor(p, 16, 64);
        p += __shfl_xor(p, 32, 64);
        if (lane < 16) sLog[bloc * 36 + j] = p;   // lane<16 => lb==lane, b=bloc
      }
      __syncthreads();
      // batched read of 32 logits (8x ds_read_b128, pipelined)
      f32x4 et[8];
      #pragma unroll
      for (int r = 0; r < 8; ++r) et[r] = *(const f32x4*)(&sLog[bloc * 36 + r * 4]);
      // softmax without max-subtraction: |logit| < ~32, exp safe in fp32
      float ssum = 0.f;
      #pragma unroll
      for (int r = 0; r < 8; ++r){
        et[r].x = __expf(et[r].x); et[r].y = __expf(et[r].y);
        et[r].z = __expf(et[r].z); et[r].w = __expf(et[r].w);
        ssum += (et[r].x + et[r].y) + (et[r].z + et[r].w);
      }
      float inv = 1.0f / ssum;
      // phase 2: recompute u, accumulate c*u (c from registers)
      #pragma unroll
      for (int tj = 0; tj < 16; ++tj){
        int j = jhalf * 16 + tj;
        short8 al8 = *(const short8*)(&sW[buf][j * 256 + lb * 16 + q1 * 8]);
        short8 afrag = (lq < 2) ? al8 : zero8;
        f32x4 u = __builtin_amdgcn_mfma_f32_16x16x32_bf16(afrag, bfrag, zf4, 0, 0, 0);
        float c = ((const float*)&et[jhalf * 4 + (tj >> 2)])[tj & 3] * inv;
        acc[tj].x += c * u.x;
        acc[tj].y += c * u.y;
        acc[tj].z += c * u.z;
        acc[tj].w += c * u.w;
      }
    }
    __syncthreads();
  }

  float* dst = partials + ((size_t)blockIdx.x * 4 + (size_t)w) * 4096 + (size_t)lane * 64;
  #pragma unroll
  for (int tj = 0; tj < 16; ++tj) *(f32x4*)(dst + tj * 4) = acc[tj];
}

// ---------------- legacy pass (round-3, fp32 inputs) — fallback if ws is small
template<int MODE>
__global__ __launch_bounds__(256)
void caps_pass_legacy(const float* __restrict__ Wg, const float* __restrict__ Xg,
                      const float* __restrict__ vbuf, float* __restrict__ partials, int CI)
{
  __shared__ __align__(16) unsigned short sW[2][8192];
  __shared__ __align__(16) unsigned int   sXd[2][256];
  __shared__ float sLog[(MODE == 1) ? (32 * 33) : 4];
  const int t = threadIdx.x, w = t >> 6, lane = t & 63;
  const int wtile = w & 1, jhalf = w >> 1, lq = lane >> 4, lb = lane & 15, q1 = lq & 1;
  const int bhalf = blockIdx.x & 1, iblk = blockIdx.x >> 1;
  const int bloc = wtile * 16 + lb, bg = bhalf * 32 + bloc;
  const size_t i0 = (size_t)iblk * (size_t)CI;
  const short8 zero8 = {0,0,0,0,0,0,0,0};
  const f32x4 zf4 = {0.f,0.f,0.f,0.f};
  f32x4 acc[16];
  #pragma unroll
  for (int tj = 0; tj < 16; ++tj) acc[tj] = zf4;
  unsigned int vpl[16], vph[16];
  if constexpr (MODE == 1){
    #pragma unroll
    for (int tj = 0; tj < 16; ++tj){
      f32x4 v = *(const f32x4*)(&vbuf[bg * 512 + (jhalf * 16 + tj) * 16 + lq * 4]);
      vpl[tj] = packbf2(v.x, v.y); vph[tj] = packbf2(v.z, v.w);
    }
  }
  {
    const float* wsrc = Wg + i0 * 8192;
    #pragma unroll
    for (int r = 0; r < 4; ++r){
      int c = r * 256 + t;
      f32x4 a = *(const f32x4*)(&wsrc[c * 8]);
      f32x4 b = *(const f32x4*)(&wsrc[c * 8 + 4]);
      *(uint4v*)(&sW[0][c * 8]) = cvt8(a, b);
    }
    int bidx = bhalf * 32 + (t >> 3), e2 = t & 7;
    f32x2 xv = *(const f32x2*)(&Xg[((size_t)bidx * NI + i0) * 16 + e2 * 2]);
    sXd[0][t] = packbf2(xv.x, xv.y);
  }
  __syncthreads();
  for (int s = 0; s < CI; ++s){
    const int buf = s & 1;
    f32x4 wpa[4], wpb[4]; f32x2 xp;
    const bool more = (s + 1 < CI);
    if (more){
      const float* wsrc = Wg + (i0 + (size_t)(s + 1)) * 8192;
      #pragma unroll
      for (int r = 0; r < 4; ++r){
        int c = r * 256 + t;
        wpa[r] = *(const f32x4*)(&wsrc[c * 8]);
        wpb[r] = *(const f32x4*)(&wsrc[c * 8 + 4]);
      }
      int bidx = bhalf * 32 + (t >> 3), e2 = t & 7;
      xp = *(const f32x2*)(&Xg[((size_t)bidx * NI + i0 + s + 1) * 16 + e2 * 2]);
    }
    const unsigned short* xrow = (const unsigned short*)&sXd[buf][0];
    short8 bl8 = *(const short8*)(&xrow[bloc * 16 + q1 * 8]);
    short8 bfrag = (lq < 2) ? bl8 : zero8;
    if constexpr (MODE == 0){
      #pragma unroll
      for (int tj = 0; tj < 16; ++tj){
        int j = jhalf * 16 + tj;
        short8 al8 = *(const short8*)(&sW[buf][j * 256 + lb * 16 + q1 * 8]);
        short8 afrag = (lq < 2) ? al8 : zero8;
        acc[tj] = __builtin_amdgcn_mfma_f32_16x16x32_bf16(afrag, bfrag, acc[tj], 0, 0, 0);
      }
    } else {
      #pragma unroll
      for (int tj = 0; tj < 16; ++tj){
        int j = jhalf * 16 + tj;
        short8 al8 = *(const short8*)(&sW[buf][j * 256 + lb * 16 + q1 * 8]);
        short8 afrag = (lq < 2) ? al8 : zero8;
        f32x4 u = __builtin_amdgcn_mfma_f32_16x16x32_bf16(afrag, bfrag, zf4, 0, 0, 0);
        float p = u.x * bflo(vpl[tj]) + u.y * bfhi(vpl[tj])
                + u.z * bflo(vph[tj]) + u.w * bfhi(vph[tj]);
        p += __shfl_xor(p, 16, 64);
        p += __shfl_xor(p, 32, 64);
        if (lane < 16) sLog[bloc * 33 + j] = p;
      }
      __syncthreads();
      const float* logrow = &sLog[bloc * 33];
      float ssum = 0.f;
      #pragma unroll
      for (int jj = 0; jj < 32; ++jj) ssum += __expf(logrow[jj]);
      float inv = 1.0f / ssum;
      #pragma unroll
      for (int tj = 0; tj < 16; ++tj){
        int j = jhalf * 16 + tj;
        short8 al8 = *(const short8*)(&sW[buf][j * 256 + lb * 16 + q1 * 8]);
        short8 afrag = (lq < 2) ? al8 : zero8;
        f32x4 u = __builtin_amdgcn_mfma_f32_16x16x32_bf16(afrag, bfrag, zf4, 0, 0, 0);
        float c = __expf(logrow[j]) * inv;
        acc[tj].x += c * u.x; acc[tj].y += c * u.y;
        acc[tj].z += c * u.z; acc[tj].w += c * u.w;
      }
    }
    if (more){
      const int nb = buf ^ 1;
      #pragma unroll
      for (int r = 0; r < 4; ++r){
        int c = r * 256 + t;
        *(uint4v*)(&sW[nb][c * 8]) = cvt8(wpa[r], wpb[r]);
      }
      sXd[nb][t] = packbf2(xp.x, xp.y);
    }
    __syncthreads();
  }
  float* dst = partials + ((size_t)blockIdx.x * 4 + (size_t)w) * 4096 + (size_t)lane * 64;
  #pragma unroll
  for (int tj = 0; tj < 16; ++tj) *(f32x4*)(dst + tj * 4) = acc[tj];
}

// ---------------- reduce + squash (unchanged)
template<int NBLK>
__global__ __launch_bounds__(128)
void caps_reduce(const float* __restrict__ partials, float* __restrict__ S_buf, float scale)
{
  const int T = blockIdx.x * 128 + threadIdx.x;
  float s0 = 0.f, s1 = 0.f, s2 = 0.f, s3 = 0.f;
  #pragma unroll
  for (int bl = 0; bl < NBLK; bl += 4){
    s0 += partials[(size_t)(bl + 0) * 32768 + T];
    s1 += partials[(size_t)(bl + 1) * 32768 + T];
    s2 += partials[(size_t)(bl + 2) * 32768 + T];
    s3 += partials[(size_t)(bl + 3) * 32768 + T];
  }
  float s = ((s0 + s1) + (s2 + s3)) * scale;
  const int bhalf = T >> 14, w = (T >> 12) & 3, l = (T >> 6) & 63, k = T & 63;
  const int b  = bhalf * 32 + (w & 1) * 16 + (l & 15);
  const int jd = ((w >> 1) * 16 + (k >> 2)) * 16 + ((l >> 4) << 2) + (k & 3);
  S_buf[b * 512 + jd] = s;
}

__global__ __launch_bounds__(256)
void caps_squash_j(const float* __restrict__ S, const float* __restrict__ vprev,
                   float* __restrict__ vout)
{
  const int b = blockIdx.x, t = threadIdx.x;
  __shared__ float sq[16];
  if (t < 16) sq[t] = 0.f;
  __syncthreads();
  float s0 = S[b * 512 + t], s1 = S[b * 512 + 256 + t];
  atomicAdd(&sq[t & 15], s0 * s0 + s1 * s1);
  __syncthreads();
  float q = sq[t & 15];
  float f = q / ((1.f + q) * sqrtf(q + 1e-8f));
  float v0 = s0 * f, v1 = s1 * f;
  if (vprev){ v0 += vprev[b * 512 + t]; v1 += vprev[b * 512 + 256 + t]; }
  vout[b * 512 + t] = v0;
  vout[b * 512 + 256 + t] = v1;
}

__global__ __launch_bounds__(256)
void caps_squash_d(const float* __restrict__ S, float* __restrict__ out)
{
  const int b = blockIdx.x, t = threadIdx.x;
  __shared__ float sq[32];
  if (t < 32) sq[t] = 0.f;
  __syncthreads();
  float s0 = S[b * 512 + t], s1 = S[b * 512 + 256 + t];
  atomicAdd(&sq[t >> 4], s0 * s0);
  atomicAdd(&sq[(t + 256) >> 4], s1 * s1);
  __syncthreads();
  float q0 = sq[t >> 4], q1 = sq[(t + 256) >> 4];
  out[b * 512 + t]       = s0 * q0 / ((1.f + q0) * sqrtf(q0 + 1e-8f));
  out[b * 512 + 256 + t] = s1 * q1 / ((1.f + q1) * sqrtf(q1 + 1e-8f));
}

extern "C" void kernel_launch(void* const* d_in, const int* in_sizes, int n_in,
                              void* d_out, int out_size, void* d_ws, size_t ws_size,
                              hipStream_t stream)
{
  const float* X = (const float*)d_in[0];  // fp32 [64][2048][16]
  const float* W = (const float*)d_in[1];  // fp32 [2048][32][16][16]
  float* wsf = (float*)d_ws;

  const size_t FP = (size_t)256 * 32768;                       // partials floats (NBI=256)
  const size_t WB_ELE = (size_t)NI * 8192, XB_ELE = (size_t)NI * 64 * 16;
  const size_t need_full = (FP + 3 * 32768) * 4 + (WB_ELE + XB_ELE) * 2;

  if (ws_size >= need_full){
    float* partials = wsf;
    float* sbuf = wsf + FP;
    float* v1   = sbuf + 32768;
    float* v12  = v1 + 32768;
    u16* Wb = (u16*)(v12 + 32768);
    u16* Xb = Wb + WB_ELE;

    caps_prep<<<dim3(8704), dim3(256), 0, stream>>>(W, X, Wb, Xb);

    caps_pass_f<0><<<dim3(512), dim3(256), 0, stream>>>(Wb, Xb, nullptr, partials, 8);
    caps_reduce<256><<<dim3(256), dim3(128), 0, stream>>>(partials, sbuf, 1.0f / 32.0f);
    caps_squash_j<<<dim3(64), dim3(256), 0, stream>>>(sbuf, nullptr, v1);

    caps_pass_f<1><<<dim3(512), dim3(256), 0, stream>>>(Wb, Xb, v1, partials, 8);
    caps_reduce<256><<<dim3(256), dim3(128), 0, stream>>>(partials, sbuf, 1.0f);
    caps_squash_j<<<dim3(64), dim3(256), 0, stream>>>(sbuf, v1, v12);

    caps_pass_f<1><<<dim3(512), dim3(256), 0, stream>>>(Wb, Xb, v12, partials, 8);
    caps_reduce<256><<<dim3(256), dim3(128), 0, stream>>>(partials, sbuf, 1.0f);
    caps_squash_d<<<dim3(64), dim3(256), 0, stream>>>(sbuf, (float*)d_out);
  } else {
    // legacy ladder (round-3 path)
    int NBI = 256;
    auto need = [](int nb){ return ((size_t)nb * 32768 + 3 * 32768) * 4; };
    if (ws_size < need(256)){
      if      (ws_size >= need(64)) NBI = 64;
      else if (ws_size >= need(16)) NBI = 16;
      else                          NBI = 4;
    }
    const int CI = NI / NBI;
    float* partials = wsf;
    float* sbuf = wsf + (size_t)NBI * 32768;
    float* v1   = sbuf + 32768;
    float* v12  = v1 + 32768;
    auto reduce = [&](float scale){
      if      (NBI == 256) caps_reduce<256><<<dim3(256), dim3(128), 0, stream>>>(partials, sbuf, scale);
      else if (NBI ==  64) caps_reduce< 64><<<dim3(256), dim3(128), 0, stream>>>(partials, sbuf, scale);
      else if (NBI ==  16) caps_reduce< 16><<<dim3(256), dim3(128), 0, stream>>>(partials, sbuf, scale);
      else                 caps_reduce<  4><<<dim3(256), dim3(128), 0, stream>>>(partials, sbuf, scale);
    };
    caps_pass_legacy<0><<<dim3(2 * NBI), dim3(256), 0, stream>>>(W, X, nullptr, partials, CI);
    reduce(1.0f / 32.0f);
    caps_squash_j<<<dim3(64), dim3(256), 0, stream>>>(sbuf, nullptr, v1);
    caps_pass_legacy<1><<<dim3(2 * NBI), dim3(256), 0, stream>>>(W, X, v1, partials, CI);
    reduce(1.0f);
    caps_squash_j<<<dim3(64), dim3(256), 0, stream>>>(sbuf, v1, v12);
    caps_pass_legacy<1><<<dim3(2 * NBI), dim3(256), 0, stream>>>(W, X, v12, partials, CI);
    reduce(1.0f);
    caps_squash_d<<<dim3(64), dim3(256), 0, stream>>>(sbuf, (float*)d_out);
  }
}

// Round 5
// 233.359 us; speedup vs baseline: 2.0621x; 1.2537x over previous
//
#include <hip/hip_runtime.h>

typedef __attribute__((ext_vector_type(8))) short short8;
typedef __attribute__((ext_vector_type(4))) float f32x4;
typedef __attribute__((ext_vector_type(2))) float f32x2;
typedef __attribute__((ext_vector_type(4))) unsigned int uint4v;
typedef unsigned short u16;

#define NI 2048   // input capsules
// B=64, J=32, D=16, E=16, JD=512. Inputs fp32; compute bf16 MFMA.

// bf16 RNE pack of two floats -> dword (lo=a, hi=b)
__device__ __forceinline__ unsigned int packbf2(float a, float b){
  unsigned int ua = __float_as_uint(a), ub = __float_as_uint(b);
  unsigned int ra = (ua + 0x7FFFu + ((ua >> 16) & 1u)) >> 16;
  unsigned int rb = (ub + 0x7FFFu + ((ub >> 16) & 1u)) & 0xFFFF0000u;
  return ra | rb;
}
__device__ __forceinline__ float bflo(unsigned int p){ return __uint_as_float(p << 16); }
__device__ __forceinline__ float bfhi(unsigned int p){ return __uint_as_float(p & 0xFFFF0000u); }

__device__ __forceinline__ uint4v cvt8(const f32x4& a, const f32x4& b){
  uint4v p = { packbf2(a.x, a.y), packbf2(a.z, a.w),
               packbf2(b.x, b.y), packbf2(b.z, b.w) };
  return p;
}

// async global->LDS, 16 B per lane; lds dest = wave-uniform base + lane*16
__device__ __forceinline__ void gl_lds16(const void* g, void* l){
  __builtin_amdgcn_global_load_lds(
      (const __attribute__((address_space(1))) unsigned int*)g,
      (__attribute__((address_space(3))) unsigned int*)l, 16, 0, 0);
}

// ---------------- prep: W fp32->bf16 (same layout), X fp32->bf16 transposed to [i][b][e]
__global__ __launch_bounds__(256)
void caps_prep(const float* __restrict__ W, const float* __restrict__ X,
               u16* __restrict__ Wb, u16* __restrict__ Xb)
{
  const int bid = blockIdx.x;
  if (bid < 8192){
    size_t base = (size_t)bid * 2048 + (size_t)threadIdx.x * 8;
    f32x4 a = *(const f32x4*)(W + base);
    f32x4 b = *(const f32x4*)(W + base + 4);
    *(uint4v*)(Wb + base) = cvt8(a, b);
  } else {
    int p = (bid - 8192) * 256 + threadIdx.x;   // 0..131071 = (i,b)
    int i = p >> 6, b = p & 63;
    const float* src = X + ((size_t)b * NI + i) * 16;
    f32x4 a0 = *(const f32x4*)(src);
    f32x4 a1 = *(const f32x4*)(src + 4);
    f32x4 a2 = *(const f32x4*)(src + 8);
    f32x4 a3 = *(const f32x4*)(src + 12);
    *(uint4v*)(Xb + (size_t)p * 16)     = cvt8(a0, a1);
    *(uint4v*)(Xb + (size_t)p * 16 + 8) = cvt8(a2, a3);
  }
}

// ---------------- fast pass (bf16 inputs, async staging, register softmax)
// MODE 0: uniform c -> partials of sum_i u  (2 i's packed into K=32)
// MODE 1: c = softmax_j(u.v) -> partials of sum_i c*u  (register-resident u & softmax)
// Block: 256 thr = 4 waves = (2 b-tiles)x(2 j-halves); bhalf = blockIdx.x&1.
template<int MODE>
__global__ __launch_bounds__(256, 2)
void caps_pass_f(const u16* __restrict__ Wb,   // bf16 [NI][8192]
                 const u16* __restrict__ Xb,   // bf16 [NI][64][16]  (transposed)
                 const float* __restrict__ vbuf,
                 float* __restrict__ partials, int CI)
{
  constexpr int WR = (MODE == 0) ? 2 : 1;     // i-rows per step
  __shared__ __align__(16) u16 sW[2][WR * 8192];
  __shared__ __align__(16) u16 sX[2][WR * 512];
  __shared__ float sSum[4][16];               // per-wave partial softmax sums (MODE 1)

  const int t     = threadIdx.x;
  const int w     = t >> 6;
  const int lane  = t & 63;
  const int wtile = w & 1;
  const int jhalf = w >> 1;
  const int lq    = lane >> 4;
  const int lb    = lane & 15;
  const int q1    = lq & 1;
  const int bhalf = blockIdx.x & 1;
  const int iblk  = blockIdx.x >> 1;
  const int bloc  = wtile * 16 + lb;
  const int bg    = bhalf * 32 + bloc;
  const size_t i0 = (size_t)iblk * (size_t)CI;

  const short8 zero8 = {0,0,0,0,0,0,0,0};
  const f32x4  zf4   = {0.f,0.f,0.f,0.f};

  f32x4 acc[16];
  #pragma unroll
  for (int tj = 0; tj < 16; ++tj) acc[tj] = zf4;

  unsigned int vpl[16], vph[16];
  if constexpr (MODE == 1){
    #pragma unroll
    for (int tj = 0; tj < 16; ++tj){
      f32x4 v = *(const f32x4*)(&vbuf[bg * 512 + (jhalf * 16 + tj) * 16 + lq * 4]);
      vpl[tj] = packbf2(v.x, v.y);
      vph[tj] = packbf2(v.z, v.w);
    }
  }

  // async stage of WR rows starting at irow into buffer nb
  auto stage = [&](int nb, size_t irow){
    #pragma unroll
    for (int rr = 0; rr < WR; ++rr){
      const u16* src = Wb + (irow + rr) * 8192 + (size_t)(w * 4) * 512;
      u16* dst = &sW[nb][rr * 8192 + w * 4 * 512];
      #pragma unroll
      for (int r = 0; r < 4; ++r)
        gl_lds16(src + r * 512 + lane * 8, dst + r * 512);
    }
    if (w >= 4 - WR){                          // last WR waves each stage one X row
      int rr = w - (4 - WR);
      gl_lds16(Xb + ((irow + rr) * 64 + (size_t)bhalf * 32) * 16 + lane * 8,
               &sX[nb][rr * 512]);
    }
  };

  const int NSTEP = CI / WR;
  stage(0, i0);
  __syncthreads();

  for (int s = 0; s < NSTEP; ++s){
    const int buf = s & 1;
    if (s + 1 < NSTEP) stage(buf ^ 1, i0 + (size_t)(s + 1) * WR);  // async

    if constexpr (MODE == 0){
      // K=32 = (e of i0 | e of i1): quads 0,1 -> row 0; quads 2,3 -> row 1
      const int rsel = lq >> 1;
      short8 bfrag = *(const short8*)(&sX[buf][rsel * 512 + bloc * 16 + q1 * 8]);
      #pragma unroll
      for (int tj = 0; tj < 16; ++tj){
        int j = jhalf * 16 + tj;
        short8 afrag = *(const short8*)(&sW[buf][rsel * 8192 + j * 256 + lb * 16 + q1 * 8]);
        acc[tj] = __builtin_amdgcn_mfma_f32_16x16x32_bf16(afrag, bfrag, acc[tj], 0, 0, 0);
      }
    } else {
      short8 bl8 = *(const short8*)(&sX[buf][bloc * 16 + q1 * 8]);
      short8 bfrag = (lq < 2) ? bl8 : zero8;    // K upper half zero
      f32x4 ut[16];
      float e[16];
      float ps = 0.f;
      // phase 1: u tiles (kept in regs) -> per-lane logits -> exps
      #pragma unroll
      for (int tj = 0; tj < 16; ++tj){
        int j = jhalf * 16 + tj;
        short8 al8 = *(const short8*)(&sW[buf][j * 256 + lb * 16 + q1 * 8]);
        short8 afrag = (lq < 2) ? al8 : zero8;
        ut[tj] = __builtin_amdgcn_mfma_f32_16x16x32_bf16(afrag, bfrag, zf4, 0, 0, 0);
        float p = ut[tj].x * bflo(vpl[tj]) + ut[tj].y * bfhi(vpl[tj])
                + ut[tj].z * bflo(vph[tj]) + ut[tj].w * bfhi(vph[tj]);
        p += __shfl_xor(p, 16, 64);
        p += __shfl_xor(p, 32, 64);   // every lane: full logit[j][b=its col]
        e[tj] = __expf(p);            // no max-subtraction: |logit| small, fp32-safe
        ps += e[tj];
      }
      // exchange partial denominator with the other j-half wave (same wtile)
      if (lane < 16) sSum[w][lane] = ps;
      __syncthreads();
      float inv = 1.0f / (ps + sSum[w ^ 2][lb]);
      // phase 2: accumulate c*u from registers
      #pragma unroll
      for (int tj = 0; tj < 16; ++tj){
        float c = e[tj] * inv;
        acc[tj].x += c * ut[tj].x;
        acc[tj].y += c * ut[tj].y;
        acc[tj].z += c * ut[tj].z;
        acc[tj].w += c * ut[tj].w;
      }
    }
    __syncthreads();
  }

  float* dst = partials + ((size_t)blockIdx.x * 4 + (size_t)w) * 4096 + (size_t)lane * 64;
  #pragma unroll
  for (int tj = 0; tj < 16; ++tj) *(f32x4*)(dst + tj * 4) = acc[tj];
}

// ---------------- legacy pass (round-3, fp32 inputs) — fallback if ws is small
template<int MODE>
__global__ __launch_bounds__(256)
void caps_pass_legacy(const float* __restrict__ Wg, const float* __restrict__ Xg,
                      const float* __restrict__ vbuf, float* __restrict__ partials, int CI)
{
  __shared__ __align__(16) unsigned short sW[2][8192];
  __shared__ __align__(16) unsigned int   sXd[2][256];
  __shared__ float sLog[(MODE == 1) ? (32 * 33) : 4];
  const int t = threadIdx.x, w = t >> 6, lane = t & 63;
  const int wtile = w & 1, jhalf = w >> 1, lq = lane >> 4, lb = lane & 15, q1 = lq & 1;
  const int bhalf = blockIdx.x & 1, iblk = blockIdx.x >> 1;
  const int bloc = wtile * 16 + lb, bg = bhalf * 32 + bloc;
  const size_t i0 = (size_t)iblk * (size_t)CI;
  const short8 zero8 = {0,0,0,0,0,0,0,0};
  const f32x4 zf4 = {0.f,0.f,0.f,0.f};
  f32x4 acc[16];
  #pragma unroll
  for (int tj = 0; tj < 16; ++tj) acc[tj] = zf4;
  unsigned int vpl[16], vph[16];
  if constexpr (MODE == 1){
    #pragma unroll
    for (int tj = 0; tj < 16; ++tj){
      f32x4 v = *(const f32x4*)(&vbuf[bg * 512 + (jhalf * 16 + tj) * 16 + lq * 4]);
      vpl[tj] = packbf2(v.x, v.y); vph[tj] = packbf2(v.z, v.w);
    }
  }
  {
    const float* wsrc = Wg + i0 * 8192;
    #pragma unroll
    for (int r = 0; r < 4; ++r){
      int c = r * 256 + t;
      f32x4 a = *(const f32x4*)(&wsrc[c * 8]);
      f32x4 b = *(const f32x4*)(&wsrc[c * 8 + 4]);
      *(uint4v*)(&sW[0][c * 8]) = cvt8(a, b);
    }
    int bidx = bhalf * 32 + (t >> 3), e2 = t & 7;
    f32x2 xv = *(const f32x2*)(&Xg[((size_t)bidx * NI + i0) * 16 + e2 * 2]);
    sXd[0][t] = packbf2(xv.x, xv.y);
  }
  __syncthreads();
  for (int s = 0; s < CI; ++s){
    const int buf = s & 1;
    f32x4 wpa[4], wpb[4]; f32x2 xp;
    const bool more = (s + 1 < CI);
    if (more){
      const float* wsrc = Wg + (i0 + (size_t)(s + 1)) * 8192;
      #pragma unroll
      for (int r = 0; r < 4; ++r){
        int c = r * 256 + t;
        wpa[r] = *(const f32x4*)(&wsrc[c * 8]);
        wpb[r] = *(const f32x4*)(&wsrc[c * 8 + 4]);
      }
      int bidx = bhalf * 32 + (t >> 3), e2 = t & 7;
      xp = *(const f32x2*)(&Xg[((size_t)bidx * NI + i0 + s + 1) * 16 + e2 * 2]);
    }
    const unsigned short* xrow = (const unsigned short*)&sXd[buf][0];
    short8 bl8 = *(const short8*)(&xrow[bloc * 16 + q1 * 8]);
    short8 bfrag = (lq < 2) ? bl8 : zero8;
    if constexpr (MODE == 0){
      #pragma unroll
      for (int tj = 0; tj < 16; ++tj){
        int j = jhalf * 16 + tj;
        short8 al8 = *(const short8*)(&sW[buf][j * 256 + lb * 16 + q1 * 8]);
        short8 afrag = (lq < 2) ? al8 : zero8;
        acc[tj] = __builtin_amdgcn_mfma_f32_16x16x32_bf16(afrag, bfrag, acc[tj], 0, 0, 0);
      }
    } else {
      #pragma unroll
      for (int tj = 0; tj < 16; ++tj){
        int j = jhalf * 16 + tj;
        short8 al8 = *(const short8*)(&sW[buf][j * 256 + lb * 16 + q1 * 8]);
        short8 afrag = (lq < 2) ? al8 : zero8;
        f32x4 u = __builtin_amdgcn_mfma_f32_16x16x32_bf16(afrag, bfrag, zf4, 0, 0, 0);
        float p = u.x * bflo(vpl[tj]) + u.y * bfhi(vpl[tj])
                + u.z * bflo(vph[tj]) + u.w * bfhi(vph[tj]);
        p += __shfl_xor(p, 16, 64);
        p += __shfl_xor(p, 32, 64);
        if (lane < 16) sLog[bloc * 33 + j] = p;
      }
      __syncthreads();
      const float* logrow = &sLog[bloc * 33];
      float ssum = 0.f;
      #pragma unroll
      for (int jj = 0; jj < 32; ++jj) ssum += __expf(logrow[jj]);
      float inv = 1.0f / ssum;
      #pragma unroll
      for (int tj = 0; tj < 16; ++tj){
        int j = jhalf * 16 + tj;
        short8 al8 = *(const short8*)(&sW[buf][j * 256 + lb * 16 + q1 * 8]);
        short8 afrag = (lq < 2) ? al8 : zero8;
        f32x4 u = __builtin_amdgcn_mfma_f32_16x16x32_bf16(afrag, bfrag, zf4, 0, 0, 0);
        float c = __expf(logrow[j]) * inv;
        acc[tj].x += c * u.x; acc[tj].y += c * u.y;
        acc[tj].z += c * u.z; acc[tj].w += c * u.w;
      }
    }
    if (more){
      const int nb = buf ^ 1;
      #pragma unroll
      for (int r = 0; r < 4; ++r){
        int c = r * 256 + t;
        *(uint4v*)(&sW[nb][c * 8]) = cvt8(wpa[r], wpb[r]);
      }
      sXd[nb][t] = packbf2(xp.x, xp.y);
    }
    __syncthreads();
  }
  float* dst = partials + ((size_t)blockIdx.x * 4 + (size_t)w) * 4096 + (size_t)lane * 64;
  #pragma unroll
  for (int tj = 0; tj < 16; ++tj) *(f32x4*)(dst + tj * 4) = acc[tj];
}

// ---------------- reduce + squash
template<int NBLK>
__global__ __launch_bounds__(128)
void caps_reduce(const float* __restrict__ partials, float* __restrict__ S_buf, float scale)
{
  const int T = blockIdx.x * 128 + threadIdx.x;
  float s0 = 0.f, s1 = 0.f, s2 = 0.f, s3 = 0.f;
  #pragma unroll
  for (int bl = 0; bl < NBLK; bl += 4){
    s0 += partials[(size_t)(bl + 0) * 32768 + T];
    s1 += partials[(size_t)(bl + 1) * 32768 + T];
    s2 += partials[(size_t)(bl + 2) * 32768 + T];
    s3 += partials[(size_t)(bl + 3) * 32768 + T];
  }
  float s = ((s0 + s1) + (s2 + s3)) * scale;
  const int bhalf = T >> 14, w = (T >> 12) & 3, l = (T >> 6) & 63, k = T & 63;
  const int b  = bhalf * 32 + (w & 1) * 16 + (l & 15);
  const int jd = ((w >> 1) * 16 + (k >> 2)) * 16 + ((l >> 4) << 2) + (k & 3);
  S_buf[b * 512 + jd] = s;
}

__global__ __launch_bounds__(256)
void caps_squash_j(const float* __restrict__ S, const float* __restrict__ vprev,
                   float* __restrict__ vout)
{
  const int b = blockIdx.x, t = threadIdx.x;
  __shared__ float sq[16];
  if (t < 16) sq[t] = 0.f;
  __syncthreads();
  float s0 = S[b * 512 + t], s1 = S[b * 512 + 256 + t];
  atomicAdd(&sq[t & 15], s0 * s0 + s1 * s1);
  __syncthreads();
  float q = sq[t & 15];
  float f = q / ((1.f + q) * sqrtf(q + 1e-8f));
  float v0 = s0 * f, v1 = s1 * f;
  if (vprev){ v0 += vprev[b * 512 + t]; v1 += vprev[b * 512 + 256 + t]; }
  vout[b * 512 + t] = v0;
  vout[b * 512 + 256 + t] = v1;
}

__global__ __launch_bounds__(256)
void caps_squash_d(const float* __restrict__ S, float* __restrict__ out)
{
  const int b = blockIdx.x, t = threadIdx.x;
  __shared__ float sq[32];
  if (t < 32) sq[t] = 0.f;
  __syncthreads();
  float s0 = S[b * 512 + t], s1 = S[b * 512 + 256 + t];
  atomicAdd(&sq[t >> 4], s0 * s0);
  atomicAdd(&sq[(t + 256) >> 4], s1 * s1);
  __syncthreads();
  float q0 = sq[t >> 4], q1 = sq[(t + 256) >> 4];
  out[b * 512 + t]       = s0 * q0 / ((1.f + q0) * sqrtf(q0 + 1e-8f));
  out[b * 512 + 256 + t] = s1 * q1 / ((1.f + q1) * sqrtf(q1 + 1e-8f));
}

extern "C" void kernel_launch(void* const* d_in, const int* in_sizes, int n_in,
                              void* d_out, int out_size, void* d_ws, size_t ws_size,
                              hipStream_t stream)
{
  const float* X = (const float*)d_in[0];  // fp32 [64][2048][16]
  const float* W = (const float*)d_in[1];  // fp32 [2048][32][16][16]
  float* wsf = (float*)d_ws;

  const size_t FP = (size_t)256 * 32768;                       // partials floats (NBI=256)
  const size_t WB_ELE = (size_t)NI * 8192, XB_ELE = (size_t)NI * 64 * 16;
  const size_t need_full = (FP + 3 * 32768) * 4 + (WB_ELE + XB_ELE) * 2;

  if (ws_size >= need_full){
    float* partials = wsf;
    float* sbuf = wsf + FP;
    float* v1   = sbuf + 32768;
    float* v12  = v1 + 32768;
    u16* Wb = (u16*)(v12 + 32768);
    u16* Xb = Wb + WB_ELE;

    caps_prep<<<dim3(8704), dim3(256), 0, stream>>>(W, X, Wb, Xb);

    caps_pass_f<0><<<dim3(512), dim3(256), 0, stream>>>(Wb, Xb, nullptr, partials, 8);
    caps_reduce<256><<<dim3(256), dim3(128), 0, stream>>>(partials, sbuf, 1.0f / 32.0f);
    caps_squash_j<<<dim3(64), dim3(256), 0, stream>>>(sbuf, nullptr, v1);

    caps_pass_f<1><<<dim3(512), dim3(256), 0, stream>>>(Wb, Xb, v1, partials, 8);
    caps_reduce<256><<<dim3(256), dim3(128), 0, stream>>>(partials, sbuf, 1.0f);
    caps_squash_j<<<dim3(64), dim3(256), 0, stream>>>(sbuf, v1, v12);

    caps_pass_f<1><<<dim3(512), dim3(256), 0, stream>>>(Wb, Xb, v12, partials, 8);
    caps_reduce<256><<<dim3(256), dim3(128), 0, stream>>>(partials, sbuf, 1.0f);
    caps_squash_d<<<dim3(64), dim3(256), 0, stream>>>(sbuf, (float*)d_out);
  } else {
    // legacy ladder (round-3 path)
    int NBI = 256;
    auto need = [](int nb){ return ((size_t)nb * 32768 + 3 * 32768) * 4; };
    if (ws_size < need(256)){
      if      (ws_size >= need(64)) NBI = 64;
      else if (ws_size >= need(16)) NBI = 16;
      else                          NBI = 4;
    }
    const int CI = NI / NBI;
    float* partials = wsf;
    float* sbuf = wsf + (size_t)NBI * 32768;
    float* v1   = sbuf + 32768;
    float* v12  = v1 + 32768;
    auto reduce = [&](float scale){
      if      (NBI == 256) caps_reduce<256><<<dim3(256), dim3(128), 0, stream>>>(partials, sbuf, scale);
      else if (NBI ==  64) caps_reduce< 64><<<dim3(256), dim3(128), 0, stream>>>(partials, sbuf, scale);
      else if (NBI ==  16) caps_reduce< 16><<<dim3(256), dim3(128), 0, stream>>>(partials, sbuf, scale);
      else                 caps_reduce<  4><<<dim3(256), dim3(128), 0, stream>>>(partials, sbuf, scale);
    };
    caps_pass_legacy<0><<<dim3(2 * NBI), dim3(256), 0, stream>>>(W, X, nullptr, partials, CI);
    reduce(1.0f / 32.0f);
    caps_squash_j<<<dim3(64), dim3(256), 0, stream>>>(sbuf, nullptr, v1);
    caps_pass_legacy<1><<<dim3(2 * NBI), dim3(256), 0, stream>>>(W, X, v1, partials, CI);
    reduce(1.0f);
    caps_squash_j<<<dim3(64), dim3(256), 0, stream>>>(sbuf, v1, v12);
    caps_pass_legacy<1><<<dim3(2 * NBI), dim3(256), 0, stream>>>(W, X, v12, partials, CI);
    reduce(1.0f);
    caps_squash_d<<<dim3(64), dim3(256), 0, stream>>>(sbuf, (float*)d_out);
  }
}